// Round 1
// baseline (320.725 us; speedup 1.0000x reference)
//
#include <hip/hip_runtime.h>
#include <cstdint>
#include <math.h>

#define B_   8
#define S_   1024
#define D_   1024
#define NH_  16
#define NKV_ 8
#define HD_  64
#define M_   (B_*S_)   // 8192 tokens

using bf16   = __bf16;
using bf16x4 = __attribute__((ext_vector_type(4))) __bf16;
using bf16x8 = __attribute__((ext_vector_type(8))) __bf16;
using f32x4  = __attribute__((ext_vector_type(4))) float;

// ---------------- async global->LDS, width 16 (m97 idiom) ----------------
__device__ __forceinline__ void gll16(const bf16* g, const bf16* l) {
    __builtin_amdgcn_global_load_lds(
        (const __attribute__((address_space(1))) unsigned int*)(uintptr_t)g,
        (__attribute__((address_space(3))) unsigned int*)(uintptr_t)l,
        16, 0, 0);
}

// ---------------- f32 -> bf16 elementwise ----------------
__global__ void k_cvt_bf16(const float* __restrict__ in, bf16* __restrict__ out, int n4) {
    int i = blockIdx.x * blockDim.x + threadIdx.x;
    if (i < n4) {
        float4 v = ((const float4*)in)[i];
        bf16x4 o = { (bf16)v.x, (bf16)v.y, (bf16)v.z, (bf16)v.w };
        ((bf16x4*)out)[i] = o;
    }
}

// ---------------- f32 [R][C] -> bf16 [C][R] (weight transpose) ----------------
__global__ void k_transpose_cvt(const float* __restrict__ in, bf16* __restrict__ out, int R, int C) {
    __shared__ float tile[64 * 65];
    int r0 = blockIdx.y * 64, c0 = blockIdx.x * 64;
    int t = threadIdx.x;
    #pragma unroll
    for (int it = 0; it < 16; ++it) {
        int idx = it * 256 + t;
        int r = idx >> 6, c = idx & 63;
        tile[r * 65 + c] = in[(size_t)(r0 + r) * C + c0 + c];
    }
    __syncthreads();
    #pragma unroll
    for (int it = 0; it < 16; ++it) {
        int idx = it * 256 + t;
        int c = idx >> 6, r = idx & 63;
        out[(size_t)(c0 + c) * R + r0 + r] = (bf16)tile[r * 65 + c];
    }
}

// ---------------- GEMM: C[M,N] = A[M,K] * Bt[N,K]^T  (bf16 in, OutT out) ----------------
template <typename OutT>
__global__ __launch_bounds__(256) void k_gemm_bt(const bf16* __restrict__ A, const bf16* __restrict__ Bt,
                                                 OutT* __restrict__ C, int M, int N, int K) {
    __shared__ __align__(16) bf16 aLds[128 * 64];
    __shared__ __align__(16) bf16 bLds[128 * 64];
    const int t    = threadIdx.x;
    const int lane = t & 63;
    const int w    = t >> 6;
    const int quad = lane >> 4;
    const int l16  = lane & 15;
    const int m0 = blockIdx.y * 128;
    const int n0 = blockIdx.x * 128;
    const int rm = (w >> 1) * 64;
    const int rn = (w & 1) * 64;

    f32x4 acc[4][4] = {};

    const int nkb = K >> 6;
    for (int kb = 0; kb < nkb; ++kb) {
        const int k0 = kb << 6;
        __syncthreads();  // protect LDS from previous iteration's readers
        #pragma unroll
        for (int it = 0; it < 4; ++it) {
            int ci = it * 256 + t;       // 1024 chunks of 16B per tile
            int r = ci >> 3, c = ci & 7;
            gll16(A  + (size_t)(m0 + r) * K + k0 + c * 8, aLds + ci * 8);
            gll16(Bt + (size_t)(n0 + r) * K + k0 + c * 8, bLds + ci * 8);
        }
        __syncthreads();  // compiler drains vmcnt before barrier
        #pragma unroll
        for (int kk = 0; kk < 2; ++kk) {
            bf16x8 af[4], bf[4];
            #pragma unroll
            for (int mi = 0; mi < 4; ++mi)
                af[mi] = *(const bf16x8*)&aLds[(rm + mi * 16 + l16) * 64 + kk * 32 + quad * 8];
            #pragma unroll
            for (int ni = 0; ni < 4; ++ni)
                bf[ni] = *(const bf16x8*)&bLds[(rn + ni * 16 + l16) * 64 + kk * 32 + quad * 8];
            #pragma unroll
            for (int mi = 0; mi < 4; ++mi)
                #pragma unroll
                for (int ni = 0; ni < 4; ++ni)
                    acc[mi][ni] = __builtin_amdgcn_mfma_f32_16x16x32_bf16(af[mi], bf[ni], acc[mi][ni], 0, 0, 0);
        }
    }
    #pragma unroll
    for (int mi = 0; mi < 4; ++mi)
        #pragma unroll
        for (int ni = 0; ni < 4; ++ni)
            #pragma unroll
            for (int r = 0; r < 4; ++r) {
                int row = m0 + rm + mi * 16 + quad * 4 + r;   // C/D: row = quad*4+reg
                int col = n0 + rn + ni * 16 + l16;            //      col = lane&15
                C[(size_t)row * N + col] = (OutT)acc[mi][ni][r];
            }
}

// ---------------- RoPE (interleaved pairs) + head-major scatter for q,k ----------------
__global__ void k_rope(const bf16* __restrict__ qkv, const float* __restrict__ cosg,
                       const float* __restrict__ sing, bf16* __restrict__ qd, bf16* __restrict__ kd) {
    int token = blockIdx.x;
    int b = token >> 10, s = token & 1023;
    int t = threadIdx.x;
    #pragma unroll
    for (int it = 0; it < 3; ++it) {
        int u = it * 256 + t;       // 768 (head, pair) slots
        int hh = u >> 5, i = u & 31;
        float c = cosg[s * 32 + i], sn = sing[s * 32 + i];
        int srcBase, dstBase;
        bf16* dst;
        if (hh < 16) {
            srcBase = token * 2048 + hh * 64;
            dstBase = ((b * NH_ + hh) * S_ + s) * 64;
            dst = qd;
        } else {
            int h = hh - 16;
            srcBase = token * 2048 + 1024 + h * 64;
            dstBase = ((b * NKV_ + h) * S_ + s) * 64;
            dst = kd;
        }
        float e = (float)qkv[srcBase + 2 * i];
        float o = (float)qkv[srcBase + 2 * i + 1];
        dst[dstBase + 2 * i]     = (bf16)(e * c - o * sn);
        dst[dstBase + 2 * i + 1] = (bf16)(e * sn + o * c);
    }
}

// ---------------- V transpose: qkv v-part -> vT[b][hkv][d][s] ----------------
__global__ void k_vtrans(const bf16* __restrict__ qkv, bf16* __restrict__ vt) {
    __shared__ __align__(16) bf16 tile[64 * 72];
    int bid = blockIdx.x;
    int st = bid & 15;
    int h  = (bid >> 4) & 7;
    int b  = bid >> 7;
    int s0 = st * 64;
    int t = threadIdx.x;
    #pragma unroll
    for (int it = 0; it < 2; ++it) {
        int ci = it * 256 + t;
        int r = ci >> 3, c = ci & 7;           // r = s, c = d-chunk
        *(uint4*)&tile[r * 72 + c * 8] =
            *(const uint4*)&qkv[(size_t)(b * S_ + s0 + r) * 2048 + 1536 + h * 64 + c * 8];
    }
    __syncthreads();
    #pragma unroll
    for (int it = 0; it < 2; ++it) {
        int ci = it * 256 + t;
        int d = ci >> 3, sc = ci & 7;
        bf16x8 v;
        #pragma unroll
        for (int j = 0; j < 8; ++j) v[j] = tile[(sc * 8 + j) * 72 + d];
        *(bf16x8*)&vt[(size_t)((b * NKV_ + h) * 64 + d) * S_ + s0 + sc * 8] = v;
    }
}

// ---------------- flash attention, block-causal (BLK_SIZE=8) ----------------
__global__ __launch_bounds__(256) void k_attn(const bf16* __restrict__ q, const bf16* __restrict__ k,
                                              const bf16* __restrict__ vt, bf16* __restrict__ out) {
    __shared__ __align__(16) bf16 kt[64 * 72];
    __shared__ __align__(16) bf16 vtt[64 * 72];
    __shared__ __align__(16) bf16 pl[4 * 16 * 72];
    int bid = blockIdx.x;
    int qt = bid & 15;
    int h  = (bid >> 4) & 15;
    int b  = bid >> 8;
    int q0 = qt * 64;
    int hkv = h >> 1;                       // jnp.repeat: q-head h -> kv head h/2
    int t = threadIdx.x;
    int w = t >> 6, lane = t & 63, quad = lane >> 4, l16 = lane & 15;
    int qw = q0 + w * 16;

    bf16x8 qf[2];
    const bf16* qbase = q + ((size_t)(b * NH_ + h) * S_ + qw + l16) * 64;
    qf[0] = *(const bf16x8*)(qbase + quad * 8);
    qf[1] = *(const bf16x8*)(qbase + 32 + quad * 8);

    f32x4 o[4] = {};
    float m[4] = {-INFINITY, -INFINITY, -INFINITY, -INFINITY};
    float l[4] = {0.f, 0.f, 0.f, 0.f};

    const bf16* kg = k  + (size_t)(b * NKV_ + hkv) * S_ * 64;
    const bf16* vg = vt + (size_t)(b * NKV_ + hkv) * 64 * S_;
    bf16* pw = pl + w * 16 * 72;

    int nkt = qt + 1;
    for (int kt_i = 0; kt_i < nkt; ++kt_i) {
        int k0 = kt_i * 64;
        __syncthreads();
        #pragma unroll
        for (int it = 0; it < 2; ++it) {
            int ci = it * 256 + t;
            int r = ci >> 3, c = ci & 7;
            *(uint4*)&kt[r * 72 + c * 8]  = *(const uint4*)(kg + (size_t)(k0 + r) * 64 + c * 8);
            *(uint4*)&vtt[r * 72 + c * 8] = *(const uint4*)(vg + (size_t)r * S_ + k0 + c * 8);
        }
        __syncthreads();

        f32x4 sc[4] = {};
        #pragma unroll
        for (int kk = 0; kk < 2; ++kk)
            #pragma unroll
            for (int f = 0; f < 4; ++f) {
                bf16x8 bfrag = *(const bf16x8*)&kt[(f * 16 + l16) * 72 + kk * 32 + quad * 8];
                sc[f] = __builtin_amdgcn_mfma_f32_16x16x32_bf16(qf[kk], bfrag, sc[f], 0, 0, 0);
            }

        bool diag = (kt_i == nkt - 1);  // only the last tile ever needs masking
        #pragma unroll
        for (int f = 0; f < 4; ++f)
            #pragma unroll
            for (int r = 0; r < 4; ++r) {
                float v = sc[f][r] * 0.125f;
                if (diag) {
                    int kcol = k0 + f * 16 + l16;
                    int qrow = qw + quad * 4 + r;
                    if (kcol >= ((qrow & ~7) + 8)) v = -INFINITY;
                }
                sc[f][r] = v;
            }

        float pr[4][4];
        #pragma unroll
        for (int r = 0; r < 4; ++r) {
            float mx = fmaxf(fmaxf(sc[0][r], sc[1][r]), fmaxf(sc[2][r], sc[3][r]));
            #pragma unroll
            for (int off = 8; off >= 1; off >>= 1)
                mx = fmaxf(mx, __shfl_xor(mx, off, 64));
            float mnew = fmaxf(m[r], mx);
            float alpha = __expf(m[r] - mnew);
            m[r] = mnew;
            float rs = 0.f;
            #pragma unroll
            for (int f = 0; f < 4; ++f) {
                float p = __expf(sc[f][r] - mnew);
                pr[f][r] = p;
                rs += p;
            }
            #pragma unroll
            for (int off = 8; off >= 1; off >>= 1)
                rs += __shfl_xor(rs, off, 64);
            l[r] = l[r] * alpha + rs;
            #pragma unroll
            for (int f = 0; f < 4; ++f) o[f][r] *= alpha;
        }

        // P: C-layout regs -> LDS -> A-layout frags (m120-verified transform)
        #pragma unroll
        for (int f = 0; f < 4; ++f)
            #pragma unroll
            for (int r = 0; r < 4; ++r)
                pw[(quad * 4 + r) * 72 + f * 16 + l16] = (bf16)pr[f][r];
        asm volatile("s_waitcnt lgkmcnt(0)" ::: "memory");

        #pragma unroll
        for (int kk = 0; kk < 2; ++kk) {
            bf16x8 pa = *(const bf16x8*)&pw[l16 * 72 + kk * 32 + quad * 8];
            #pragma unroll
            for (int f = 0; f < 4; ++f) {
                bf16x8 vb = *(const bf16x8*)&vtt[(f * 16 + l16) * 72 + kk * 32 + quad * 8];
                o[f] = __builtin_amdgcn_mfma_f32_16x16x32_bf16(pa, vb, o[f], 0, 0, 0);
            }
        }
    }

    #pragma unroll
    for (int r = 0; r < 4; ++r) {
        float invl = 1.0f / l[r];
        #pragma unroll
        for (int f = 0; f < 4; ++f) {
            int row = qw + quad * 4 + r;
            int col = h * 64 + f * 16 + l16;
            out[(size_t)(b * S_ + row) * 1024 + col] = (bf16)(o[f][r] * invl);
        }
    }
}

// ---------------- launch ----------------
extern "C" void kernel_launch(void* const* d_in, const int* in_sizes, int n_in,
                              void* d_out, int out_size, void* d_ws, size_t ws_size,
                              hipStream_t stream) {
    const float* x  = (const float*)d_in[0];
    const float* wq = (const float*)d_in[1];
    const float* wk = (const float*)d_in[2];
    const float* wv = (const float*)d_in[3];
    const float* wo = (const float*)d_in[4];
    const float* fc = (const float*)d_in[5];
    const float* fs = (const float*)d_in[6];
    (void)in_sizes; (void)n_in; (void)out_size; (void)ws_size;

    char* ws = (char*)d_ws;
    bf16* xb    = (bf16*)(ws);                          // 16 MB, reused as q after GEMM1
    bf16* wqkvT = (bf16*)(ws + (16u << 20));            //  4 MB  [2048][1024]
    bf16* woT   = (bf16*)(ws + (20u << 20));            //  2 MB  [1024][1024]
    bf16* qkvb  = (bf16*)(ws + (22u << 20));            // 32 MB  [8192][2048], reused as attn out
    bf16* kb    = (bf16*)(ws + (54u << 20));            //  8 MB  [8][8][1024][64]
    bf16* vtb   = (bf16*)(ws + (62u << 20));            //  8 MB  [8][8][64][1024]  (70 MB total)
    bf16* qb    = xb;
    bf16* attnb = qkvb;

    k_cvt_bf16<<<dim3(8192), dim3(256), 0, stream>>>(x, xb, (M_ * D_) / 4);
    k_transpose_cvt<<<dim3(16, 16), dim3(256), 0, stream>>>(wq, wqkvT, 1024, 1024);
    k_transpose_cvt<<<dim3( 8, 16), dim3(256), 0, stream>>>(wk, wqkvT + 1024 * 1024, 1024, 512);
    k_transpose_cvt<<<dim3( 8, 16), dim3(256), 0, stream>>>(wv, wqkvT + 1536 * 1024, 1024, 512);
    k_transpose_cvt<<<dim3(16, 16), dim3(256), 0, stream>>>(wo, woT, 1024, 1024);

    k_gemm_bt<bf16><<<dim3(16, 64), dim3(256), 0, stream>>>(xb, wqkvT, qkvb, M_, 2048, 1024);

    k_rope<<<dim3(8192), dim3(256), 0, stream>>>(qkvb, fc, fs, qb, kb);
    k_vtrans<<<dim3(1024), dim3(256), 0, stream>>>(qkvb, vtb);

    k_attn<<<dim3(2048), dim3(256), 0, stream>>>(qb, kb, vtb, attnb);

    k_gemm_bt<float><<<dim3(8, 64), dim3(256), 0, stream>>>(attnb, woT, (float*)d_out, M_, 1024, 1024);
}